// Round 3
// baseline (456.038 us; speedup 1.0000x reference)
//
#include <hip/hip_runtime.h>

// X: (16, 64, 256, 256) fp32, K: (3,3) fp32, same-shape output.
// Depthwise 3x3, stride 1, pad 1. HBM floor ~537 MB @ 6.4 TB/s ~ 85 us.
// History: R1 8-row+swizzle 450.7 agg; R2 16-row shuffle-halo 164.5 us/disp
// @2.54 TB/s; R3 8-row 3-deep pipeline <163.5 us/disp. All pinned ~160 us,
// VALU <9%, no pipe saturated -> waves too short: prologue+drain dominate,
// steady-state MLP never establishes.
// R4: one wave = one 64-row quarter-plane column (66 loads/wave, amp 1.03x);
//     one block = one plane (quarter-boundary halos re-read by sibling waves
//     on the same CU -> L1 hits); 8-slot circular row buffer, unconditional
//     clamped loads -> 6 loads in flight steady-state, counted vmcnt;
//     grid 1024 blocks (4/CU) of long-lived waves (fill kernel proves 6.4
//     TB/s at 10% occupancy with deep per-wave MLP).

#define CONV_H 256
#define CONV_W 256
#define NPLANES (16 * 64)               // B*C independent planes
#define ROWS 64                         // rows per thread (quarter plane)
#define DEPTH 8                         // circular row-buffer slots (pow2)

typedef float v4f __attribute__((ext_vector_type(4)));

struct Row { float4 c; float l, r; };

// Expand a raw float4 row into center + halo via wave shuffles.
// `valid` = 1.0 in-range / 0.0 zero-pad row (branchless).
// 64 lanes x 4 floats == 256 == W, so wave edges are exactly the image pad.
__device__ __forceinline__ Row expand_row(float4 c, int lane, float valid) {
    Row v;
    float l = __shfl_up(c.w, 1);                // lane i-1 col3 == my col-1
    float r = __shfl_down(c.x, 1);              // lane i+1 col0 == my col+4
    v.c.x = c.x * valid;
    v.c.y = c.y * valid;
    v.c.z = c.z * valid;
    v.c.w = c.w * valid;
    v.l = (lane == 0)  ? 0.f : l * valid;       // col 0 left pad
    v.r = (lane == 63) ? 0.f : r * valid;       // col 255 right pad
    return v;
}

__global__ __launch_bounds__(256)
void conv3x3_kernel(const float* __restrict__ X,
                    const float* __restrict__ Kw,
                    float* __restrict__ out)
{
    const float k00 = Kw[0], k01 = Kw[1], k02 = Kw[2];
    const float k10 = Kw[3], k11 = Kw[4], k12 = Kw[5];
    const float k20 = Kw[6], k21 = Kw[7], k22 = Kw[8];

    const int lane    = threadIdx.x & 63;       // col group (64*16B = full row)
    const int quarter = threadIdx.x >> 6;       // which 64-row band (wave id)
    const int p       = blockIdx.x;             // plane == block
    const int h0      = quarter << 6;           // 0, 64, 128, 192

    const float* colp = X   + (size_t)p * (CONV_H * CONV_W) + (lane << 2);
    float*       outp = out + (size_t)p * (CONV_H * CONV_W)
                            + (size_t)h0 * CONV_W + (lane << 2);

    // --- prologue: 8 unconditional clamped loads (rows h0-1 .. h0+6) ---
    float4 raw[DEPTH];                          // raw[j%8] = row h0-1+j
    #pragma unroll
    for (int j = 0; j < DEPTH; ++j) {
        int r   = h0 - 1 + j;
        int rcl = min(max(r, 0), CONV_H - 1);
        raw[j] = *(const float4*)(colp + rcl * CONV_W);
    }

    Row rm = expand_row(raw[0], lane, (h0 > 0) ? 1.f : 0.f);
    Row rc = expand_row(raw[1], lane, 1.f);

    // last row this wave ever needs (h0+ROWS, clamped); late prefetches
    // saturate at this address -> harmless L1 hits, keeps code straight-line
    const int rowcap = min(h0 + ROWS + 1, CONV_H - 1);

    for (int ii = 0; ii < ROWS; ii += DEPTH) {
        #pragma unroll
        for (int j = 0; j < DEPTH; ++j) {       // slot indices all static
            const int i = ii + j;
            // prefetch row h0+7+i into slot i%8 (its row h0-1+i was rolled
            // into registers two iterations ago)
            int pr = min(h0 + DEPTH - 1 + i, rowcap);
            raw[j] = *(const float4*)(colp + pr * CONV_W);

            // consume row h0+1+i from slot (i+2)%8 -> 6 loads outstanding
            const int rpr = h0 + 1 + i;
            Row rp = expand_row(raw[(j + 2) & (DEPTH - 1)], lane,
                                (rpr < CONV_H) ? 1.f : 0.f);

            float4 o;
            o.x = k00 * rm.l   + k01 * rm.c.x + k02 * rm.c.y
                + k10 * rc.l   + k11 * rc.c.x + k12 * rc.c.y
                + k20 * rp.l   + k21 * rp.c.x + k22 * rp.c.y;
            o.y = k00 * rm.c.x + k01 * rm.c.y + k02 * rm.c.z
                + k10 * rc.c.x + k11 * rc.c.y + k12 * rc.c.z
                + k20 * rp.c.x + k21 * rp.c.y + k22 * rp.c.z;
            o.z = k00 * rm.c.y + k01 * rm.c.z + k02 * rm.c.w
                + k10 * rc.c.y + k11 * rc.c.z + k12 * rc.c.w
                + k20 * rp.c.y + k21 * rp.c.z + k22 * rp.c.w;
            o.w = k00 * rm.c.z + k01 * rm.c.w + k02 * rm.r
                + k10 * rc.c.z + k11 * rc.c.w + k12 * rc.r
                + k20 * rp.c.z + k21 * rp.c.w + k22 * rp.r;

            v4f ov = { o.x, o.y, o.z, o.w };
            __builtin_nontemporal_store(ov, (v4f*)(outp + i * CONV_W));

            rm = rc;
            rc = rp;
        }
    }
}

extern "C" void kernel_launch(void* const* d_in, const int* in_sizes, int n_in,
                              void* d_out, int out_size, void* d_ws, size_t ws_size,
                              hipStream_t stream) {
    const float* X  = (const float*)d_in[0];
    const float* Kw = (const float*)d_in[1];
    float* out = (float*)d_out;

    // one block per plane: 4 waves x (64 rows x full 256-wide row)
    conv3x3_kernel<<<NPLANES, 256, 0, stream>>>(X, Kw, out);
}